// Round 15
// baseline (210.007 us; speedup 1.0000x reference)
//
#include <hip/hip_runtime.h>

#define NNODES 50000
#define NEDGES 600000
#define HID 128
#define NLAYERS 3
#define NEG 0.01f
#define SCAN_B ((NNODES + 1023) / 1024)   // 49 blocks
#define FILL_BPG 150                      // fill blocks per XCD group
#define CVT_B 12500                       // (NNODES*64)/256
#define ZERO_B 196                        // ceil((NNODES+1)/256)
#define WCONV_B 24
#define NPB 16                            // nodes per layer_k block (50000/16=3125)

typedef __attribute__((ext_vector_type(8))) short short8;
typedef __attribute__((ext_vector_type(4))) float f32x4;

__device__ __forceinline__ unsigned int f2bf(float f) {   // RNE f32 -> bf16 bits
    unsigned int u = __float_as_uint(f);
    return (u + 0x7fffu + ((u >> 16) & 1u)) >> 16;
}
__device__ __forceinline__ float bf2f(unsigned int h) {
    return __uint_as_float(h << 16);
}
__device__ __forceinline__ float bflo(unsigned int p) { return __uint_as_float(p << 16); }
__device__ __forceinline__ float bfhi(unsigned int p) { return __uint_as_float(p & 0xffff0000u); }

// ---------- prep: cvt(x->hb) | zero(off) | wconv(W->frags), one dispatch -----
__global__ __launch_bounds__(256) void prep_k(const float* __restrict__ x,
                                              unsigned int* __restrict__ hb,
                                              int* __restrict__ off,
                                              const float* __restrict__ W,
                                              uint4* __restrict__ whf,
                                              uint4* __restrict__ wlf) {
    const int b = blockIdx.x;
    const int t = threadIdx.x;
    if (b < CVT_B) {                       // x (f32) -> hb (bf16x2)
        const int i = b * 256 + t;
        const float2 v = *(const float2*)(x + (size_t)i * 2);
        hb[i] = f2bf(v.x) | (f2bf(v.y) << 16);
    } else if (b < CVT_B + ZERO_B) {       // zero the degree histogram
        const int i = (b - CVT_B) * 256 + t;
        if (i <= NNODES) off[i] = 0;
    } else {                               // W -> split-bf16 MFMA B fragments
        const int g = ((b - CVT_B - ZERO_B) * 256 + t) >> 6;
        if (g >= NLAYERS * 32) return;
        const int lane = t & 63;
        const int l = g >> 5;
        const int kt = (g >> 3) & 3;
        const int nt = g & 7;
        const int n = nt * 16 + (lane & 15);
        const int k0 = kt * 32 + (lane >> 4) * 8;
        unsigned int hh[8], ll[8];
#pragma unroll
        for (int j = 0; j < 8; ++j) {
            const float w = W[l * HID * HID + (k0 + j) * HID + n];
            const unsigned int wh = f2bf(w);
            hh[j] = wh;
            ll[j] = f2bf(w - bf2f(wh));
        }
        uint4 ph, pl;
        ph.x = hh[0] | (hh[1] << 16); ph.y = hh[2] | (hh[3] << 16);
        ph.z = hh[4] | (hh[5] << 16); ph.w = hh[6] | (hh[7] << 16);
        pl.x = ll[0] | (ll[1] << 16); pl.y = ll[2] | (ll[3] << 16);
        pl.z = ll[4] | (ll[5] << 16); pl.w = ll[6] | (ll[7] << 16);
        const int idx = ((l * 4 + kt) * 8 + nt) * 64 + lane;
        whf[idx] = ph;
        wlf[idx] = pl;
    }
}

// ---------- CSR build ----------

__global__ __launch_bounds__(256) void hist_k(const int* __restrict__ ei,
                                              int* __restrict__ deg) {
    const int e = blockIdx.x * blockDim.x + threadIdx.x;
    if (e < NEDGES) atomicAdd(&deg[ei[NEDGES + e]], 1);
}

__global__ __launch_bounds__(1024) void scan1_k(const int* __restrict__ deg,
                                                int* __restrict__ part,
                                                int* __restrict__ bsum) {
    __shared__ int s[1024];
    const int t = threadIdx.x;
    const int i = blockIdx.x * 1024 + t;
    const int v = (i < NNODES) ? deg[i] : 0;
    s[t] = v;
    __syncthreads();
    for (int d = 1; d < 1024; d <<= 1) {
        const int add = (t >= d) ? s[t - d] : 0;
        __syncthreads();
        s[t] += add;
        __syncthreads();
    }
    if (i < NNODES) part[i] = s[t] - v;
    if (t == 1023) bsum[blockIdx.x] = s[1023];
}

__global__ __launch_bounds__(1024) void scan2_k(const int* __restrict__ part,
                                                const int* __restrict__ bsum,
                                                int* __restrict__ off,
                                                int* __restrict__ cur) {
    const int b = blockIdx.x;
    const int t = threadIdx.x;
    const int lane = t & 63;
    int v = (lane < b) ? bsum[lane] : 0;
#pragma unroll
    for (int d = 1; d < 64; d <<= 1) v += __shfl_xor(v, d);
    const int i = b * 1024 + t;
    if (i < NNODES) {
        const int e = part[i] + v;
        off[i] = e;
        cur[i] = e;
    }
    if (b == 0 && t == 0) off[NNODES] = NEDGES;
}

// XCD-partitioned scatter (see R10): group g = blockIdx.x%8 owns one dst range
// so all writers of a meta line sit on one XCD L2 (kills write amplification).
__global__ __launch_bounds__(256) void fill_k(const int* __restrict__ ei,
                                              const float* __restrict__ ea,
                                              int* __restrict__ cur,
                                              unsigned long long* __restrict__ meta) {
    const int g = blockIdx.x & 7;
    const int bg = blockIdx.x >> 3;
    const int dlo = g * (NNODES / 8);
    const int dhi = dlo + (NNODES / 8);
    const int stride = FILL_BPG * 256;
    for (int e = bg * 256 + threadIdx.x; e < NEDGES; e += stride) {
        const int d = ei[NEDGES + e];
        if (d >= dlo && d < dhi) {
            const int s = ei[e];
            const float2 av = *(const float2*)(ea + 2 * e);
            const int p = atomicAdd(&cur[d], 1);
            meta[p] = (unsigned long long)(unsigned int)s |
                      ((unsigned long long)(f2bf(av.x) | (f2bf(av.y) << 16)) << 32);
        }
    }
}

// ---------- Fused layer: pipelined agg (flat edge stream) + 16x128 MFMA GEMM -
// Each wave owns 4 contiguous nodes = one contiguous meta range. Double-buffer
// meta batches so gathers(batch k) overlap meta-loads(batch k+1): ~1 latency
// round per 8 edges instead of 2 per node-batch (R14 was chain-latency-bound).
// Accumulate in a register run-acc, flushed to LDS only on node change.
__global__ __launch_bounds__(256) void layer_k(
    const unsigned int* __restrict__ hb,   // [N*64] bf16x2 node features (in)
    const unsigned long long* __restrict__ meta,
    const float* __restrict__ Wl,          // [2, HID]
    const float* __restrict__ bl,          // [HID]
    const int* __restrict__ off,
    const uint4* __restrict__ whf,         // this layer's [4][8][64] frags
    const uint4* __restrict__ wlf,
    const float* __restrict__ bias,        // [HID]
    float* __restrict__ out,               // f32 (final layer)
    unsigned short* __restrict__ hbo,      // bf16 (layers 0,1) — DISJOINT from hb
    const int last)
{
    __shared__ float lacc[4][4][64][2];    // [wave][node][lane][2 feats] = 8KB
    __shared__ unsigned int vsh[NPB * 68]; // 16 rows, pad 68
    const int tid = threadIdx.x;
    const int wave = tid >> 6;             // 0..3
    const int lane = tid & 63;
    const int nb = blockIdx.x * NPB;
    const int n0 = nb + wave * 4;

    const int f0 = lane << 1;
    const float2 w0 = *(const float2*)(Wl + f0);
    const float2 w1 = *(const float2*)(Wl + HID + f0);
    const float2 bb = *(const float2*)(bl + f0);

    // self terms (eps=0): lacc starts at h[node]
#pragma unroll
    for (int i = 0; i < 4; ++i) {
        const unsigned int hp = hb[(size_t)(n0 + i) * 64 + lane];
        lacc[wave][i][lane][0] = bflo(hp);
        lacc[wave][i][lane][1] = bfhi(hp);
    }

    const int o0 = off[n0];
    const int o1 = off[n0 + 1];
    const int o2 = off[n0 + 2];
    const int o3 = off[n0 + 3];
    const int o4 = off[n0 + 4];

    if (o0 < o4) {
        unsigned long long m[8];
#pragma unroll
        for (int j = 0; j < 8; ++j)
            m[j] = meta[min(o0 + j, o4 - 1)];
        float raccx = 0.f, raccy = 0.f;
        int dcur = 0;
        for (int idx = o0; idx < o4; idx += 8) {
            // issue 8 gathers for current batch
            unsigned int g[8];
#pragma unroll
            for (int j = 0; j < 8; ++j)
                g[j] = hb[(size_t)(unsigned int)m[j] * 64 + lane];
            // issue next meta batch (overlaps with gathers in flight)
            const int nxt = idx + 8;
            unsigned long long m2[8];
#pragma unroll
            for (int j = 0; j < 8; ++j)
                m2[j] = (nxt < o4) ? meta[min(nxt + j, o4 - 1)] : 0ull;
            // consume current batch
#pragma unroll
            for (int j = 0; j < 8; ++j) {
                const int e = idx + j;
                if (e < o4) {                      // wave-uniform
                    const int dl = (e >= o1) + (e >= o2) + (e >= o3);
                    if (dl != dcur) {              // wave-uniform, monotone
                        lacc[wave][dcur][lane][0] += raccx;
                        lacc[wave][dcur][lane][1] += raccy;
                        raccx = 0.f; raccy = 0.f;
                        dcur = dl;
                    }
                    const unsigned int ap = (unsigned int)(m[j] >> 32);
                    const float a0 = bflo(ap), a1 = bfhi(ap);
                    raccx += fmaxf(bflo(g[j]) + fmaf(a0, w0.x, fmaf(a1, w1.x, bb.x)), 0.f);
                    raccy += fmaxf(bfhi(g[j]) + fmaf(a0, w0.y, fmaf(a1, w1.y, bb.y)), 0.f);
                }
            }
#pragma unroll
            for (int j = 0; j < 8; ++j) m[j] = m2[j];
        }
        lacc[wave][dcur][lane][0] += raccx;
        lacc[wave][dcur][lane][1] += raccy;
    }

    // pack this wave's 4 rows into vsh
#pragma unroll
    for (int i = 0; i < 4; ++i) {
        const int nl = wave * 4 + i;
        vsh[nl * 68 + lane] =
            f2bf(lacc[wave][i][lane][0]) | (f2bf(lacc[wave][i][lane][1]) << 16);
    }
    __syncthreads();

    // ---- phase 2: GEMM from LDS. all waves share the 16-row A tile; each
    // wave owns a 32-col quarter (2 MFMA col-tiles). ----
    const int lrow = lane & 15;            // local A row
    short8 a[4];
#pragma unroll
    for (int kt = 0; kt < 4; ++kt) {
        const uint4 t = *(const uint4*)&vsh[lrow * 68 + (kt * 4 + (lane >> 4)) * 4];
        a[kt] = *(const short8*)&t;
    }
    const int crow0 = nb + (lane >> 4) * 4;
    const int ncol = lane & 15;
#pragma unroll
    for (int ntl = 0; ntl < 2; ++ntl) {
        const int nt = wave * 2 + ntl;
        const float bv = bias[nt * 16 + ncol];
        f32x4 acc = {bv, bv, bv, bv};
#pragma unroll
        for (int kt = 0; kt < 4; ++kt) {
            uint4 th = whf[(kt * 8 + nt) * 64 + lane];
            uint4 tl = wlf[(kt * 8 + nt) * 64 + lane];
            acc = __builtin_amdgcn_mfma_f32_16x16x32_bf16(a[kt], *(short8*)&th, acc, 0, 0, 0);
            acc = __builtin_amdgcn_mfma_f32_16x16x32_bf16(a[kt], *(short8*)&tl, acc, 0, 0, 0);
        }
#pragma unroll
        for (int r = 0; r < 4; ++r) {
            const int rr = crow0 + r;
            float v = acc[r];
            v = v >= 0.f ? v : NEG * v;
            if (last) out[(size_t)rr * HID + nt * 16 + ncol] = v;
            else      hbo[(size_t)rr * HID + nt * 16 + ncol] = (unsigned short)f2bf(v);
        }
    }
}

extern "C" void kernel_launch(void* const* d_in, const int* in_sizes, int n_in,
                              void* d_out, int out_size, void* d_ws, size_t ws_size,
                              hipStream_t stream) {
    const float* x  = (const float*)d_in[0];
    const int*   ei = (const int*)d_in[1];
    const float* ea = (const float*)d_in[2];
    const float* Wl = (const float*)d_in[3];
    const float* bl = (const float*)d_in[4];
    const float* W  = (const float*)d_in[5];
    const float* b  = (const float*)d_in[6];

    float* h = (float*)d_out;                              // final f32 output

    unsigned long long* meta = (unsigned long long*)d_ws;  // [E] {src, a0|a1 bf16}
    unsigned int* hb0 = (unsigned int*)(meta + NEDGES);    // [N*64] features ping
    unsigned int* hb1 = hb0 + (size_t)NNODES * 64;         // [N*64] features pong
    uint4* whf = (uint4*)(hb1 + (size_t)NNODES * 64);      // [3][4][8][64]
    uint4* wlf = whf + NLAYERS * 4 * 8 * 64;
    int* off  = (int*)(wlf + NLAYERS * 4 * 8 * 64);        // [N+1] (doubles as histogram)
    int* cur  = off + NNODES + 1;
    int* part = cur + NNODES;
    int* bsum = part + NNODES;

    prep_k<<<CVT_B + ZERO_B + WCONV_B, 256, 0, stream>>>(x, hb0, off, W, whf, wlf);
    hist_k<<<(NEDGES + 255) / 256, 256, 0, stream>>>(ei, off);
    scan1_k<<<SCAN_B, 1024, 0, stream>>>(off, part, bsum);
    scan2_k<<<SCAN_B, 1024, 0, stream>>>(part, bsum, off, cur);
    fill_k<<<8 * FILL_BPG, 256, 0, stream>>>(ei, ea, cur, meta);

    unsigned int* hin = hb0;
    unsigned int* hout = hb1;
    for (int l = 0; l < NLAYERS; ++l) {
        layer_k<<<NNODES / NPB, 256, 0, stream>>>(
            hin, meta, Wl + (size_t)l * 2 * HID, bl + (size_t)l * HID, off,
            whf + (size_t)l * 4 * 8 * 64, wlf + (size_t)l * 4 * 8 * 64,
            b + (size_t)l * HID, h, (unsigned short*)hout, l == NLAYERS - 1);
        unsigned int* tmp = hin; hin = hout; hout = tmp;
    }
}

// Round 16
// 188.183 us; speedup vs baseline: 1.1160x; 1.1160x over previous
//
#include <hip/hip_runtime.h>

#define NNODES 50000
#define NEDGES 600000
#define HID 128
#define NLAYERS 3
#define NEG 0.01f
#define SCAN_B ((NNODES + 1023) / 1024)   // 49 blocks
#define FILL_BPG 150                      // fill blocks per XCD group
#define CVT_B 12500                       // (NNODES*64)/256
#define ZERO_B 196                        // ceil((NNODES+1)/256)
#define WCONV_B 24
#define NPB 16                            // nodes per layer_k block (50000/16=3125)
#define MCAP 512                          // LDS meta cache entries (block mean ~192)

typedef __attribute__((ext_vector_type(8))) short short8;
typedef __attribute__((ext_vector_type(4))) float f32x4;

__device__ __forceinline__ unsigned int f2bf(float f) {   // RNE f32 -> bf16 bits
    unsigned int u = __float_as_uint(f);
    return (u + 0x7fffu + ((u >> 16) & 1u)) >> 16;
}
__device__ __forceinline__ float bf2f(unsigned int h) {
    return __uint_as_float(h << 16);
}
__device__ __forceinline__ float bflo(unsigned int p) { return __uint_as_float(p << 16); }
__device__ __forceinline__ float bfhi(unsigned int p) { return __uint_as_float(p & 0xffff0000u); }

// ---------- prep: cvt(x->hb) | zero(off) | wconv(W->frags), one dispatch -----
__global__ __launch_bounds__(256) void prep_k(const float* __restrict__ x,
                                              unsigned int* __restrict__ hb,
                                              int* __restrict__ off,
                                              const float* __restrict__ W,
                                              uint4* __restrict__ whf,
                                              uint4* __restrict__ wlf) {
    const int b = blockIdx.x;
    const int t = threadIdx.x;
    if (b < CVT_B) {                       // x (f32) -> hb (bf16x2)
        const int i = b * 256 + t;
        const float2 v = *(const float2*)(x + (size_t)i * 2);
        hb[i] = f2bf(v.x) | (f2bf(v.y) << 16);
    } else if (b < CVT_B + ZERO_B) {       // zero the degree histogram
        const int i = (b - CVT_B) * 256 + t;
        if (i <= NNODES) off[i] = 0;
    } else {                               // W -> split-bf16 MFMA B fragments
        const int g = ((b - CVT_B - ZERO_B) * 256 + t) >> 6;
        if (g >= NLAYERS * 32) return;
        const int lane = t & 63;
        const int l = g >> 5;
        const int kt = (g >> 3) & 3;
        const int nt = g & 7;
        const int n = nt * 16 + (lane & 15);
        const int k0 = kt * 32 + (lane >> 4) * 8;
        unsigned int hh[8], ll[8];
#pragma unroll
        for (int j = 0; j < 8; ++j) {
            const float w = W[l * HID * HID + (k0 + j) * HID + n];
            const unsigned int wh = f2bf(w);
            hh[j] = wh;
            ll[j] = f2bf(w - bf2f(wh));
        }
        uint4 ph, pl;
        ph.x = hh[0] | (hh[1] << 16); ph.y = hh[2] | (hh[3] << 16);
        ph.z = hh[4] | (hh[5] << 16); ph.w = hh[6] | (hh[7] << 16);
        pl.x = ll[0] | (ll[1] << 16); pl.y = ll[2] | (ll[3] << 16);
        pl.z = ll[4] | (ll[5] << 16); pl.w = ll[6] | (ll[7] << 16);
        const int idx = ((l * 4 + kt) * 8 + nt) * 64 + lane;
        whf[idx] = ph;
        wlf[idx] = pl;
    }
}

// ---------- CSR build ----------

__global__ __launch_bounds__(256) void hist_k(const int* __restrict__ ei,
                                              int* __restrict__ deg) {
    const int e = blockIdx.x * blockDim.x + threadIdx.x;
    if (e < NEDGES) atomicAdd(&deg[ei[NEDGES + e]], 1);
}

__global__ __launch_bounds__(1024) void scan1_k(const int* __restrict__ deg,
                                                int* __restrict__ part,
                                                int* __restrict__ bsum) {
    __shared__ int s[1024];
    const int t = threadIdx.x;
    const int i = blockIdx.x * 1024 + t;
    const int v = (i < NNODES) ? deg[i] : 0;
    s[t] = v;
    __syncthreads();
    for (int d = 1; d < 1024; d <<= 1) {
        const int add = (t >= d) ? s[t - d] : 0;
        __syncthreads();
        s[t] += add;
        __syncthreads();
    }
    if (i < NNODES) part[i] = s[t] - v;
    if (t == 1023) bsum[blockIdx.x] = s[1023];
}

__global__ __launch_bounds__(1024) void scan2_k(const int* __restrict__ part,
                                                const int* __restrict__ bsum,
                                                int* __restrict__ off,
                                                int* __restrict__ cur) {
    const int b = blockIdx.x;
    const int t = threadIdx.x;
    const int lane = t & 63;
    int v = (lane < b) ? bsum[lane] : 0;
#pragma unroll
    for (int d = 1; d < 64; d <<= 1) v += __shfl_xor(v, d);
    const int i = b * 1024 + t;
    if (i < NNODES) {
        const int e = part[i] + v;
        off[i] = e;
        cur[i] = e;
    }
    if (b == 0 && t == 0) off[NNODES] = NEDGES;
}

// XCD-partitioned scatter (see R10): group g = blockIdx.x%8 owns one dst range
// so all writers of a meta line sit on one XCD L2 (kills write amplification).
__global__ __launch_bounds__(256) void fill_k(const int* __restrict__ ei,
                                              const float* __restrict__ ea,
                                              int* __restrict__ cur,
                                              unsigned long long* __restrict__ meta) {
    const int g = blockIdx.x & 7;
    const int bg = blockIdx.x >> 3;
    const int dlo = g * (NNODES / 8);
    const int dhi = dlo + (NNODES / 8);
    const int stride = FILL_BPG * 256;
    for (int e = bg * 256 + threadIdx.x; e < NEDGES; e += stride) {
        const int d = ei[NEDGES + e];
        if (d >= dlo && d < dhi) {
            const int s = ei[e];
            const float2 av = *(const float2*)(ea + 2 * e);
            const int p = atomicAdd(&cur[d], 1);
            meta[p] = (unsigned long long)(unsigned int)s |
                      ((unsigned long long)(f2bf(av.x) | (f2bf(av.y) << 16)) << 32);
        }
    }
}

// Aggregation body over [e0,e1) local-meta indices; MFETCH(i) yields the entry.
#define AGG_LOOP(MFETCH)                                                        \
    for (; idx + 8 <= e1; idx += 8) {                                           \
        unsigned long long m[8];                                                \
        _Pragma("unroll")                                                       \
        for (int j = 0; j < 8; ++j) m[j] = MFETCH(idx + j);                     \
        unsigned int g[8];                                                      \
        _Pragma("unroll")                                                       \
        for (int j = 0; j < 8; ++j)                                             \
            g[j] = hb[(size_t)(unsigned int)m[j] * 64 + lane];                  \
        _Pragma("unroll")                                                       \
        for (int j = 0; j < 8; ++j) {                                           \
            const unsigned int ap = (unsigned int)(m[j] >> 32);                 \
            const float a0 = bflo(ap), a1 = bfhi(ap);                           \
            acc.x += fmaxf(bflo(g[j]) + fmaf(a0, w0.x, fmaf(a1, w1.x, bb.x)), 0.f); \
            acc.y += fmaxf(bfhi(g[j]) + fmaf(a0, w0.y, fmaf(a1, w1.y, bb.y)), 0.f); \
        }                                                                       \
    }                                                                           \
    if (idx + 4 <= e1) {                                                        \
        unsigned long long m[4];                                                \
        _Pragma("unroll")                                                       \
        for (int j = 0; j < 4; ++j) m[j] = MFETCH(idx + j);                     \
        unsigned int g[4];                                                      \
        _Pragma("unroll")                                                       \
        for (int j = 0; j < 4; ++j)                                             \
            g[j] = hb[(size_t)(unsigned int)m[j] * 64 + lane];                  \
        _Pragma("unroll")                                                       \
        for (int j = 0; j < 4; ++j) {                                           \
            const unsigned int ap = (unsigned int)(m[j] >> 32);                 \
            const float a0 = bflo(ap), a1 = bfhi(ap);                           \
            acc.x += fmaxf(bflo(g[j]) + fmaf(a0, w0.x, fmaf(a1, w1.x, bb.x)), 0.f); \
            acc.y += fmaxf(bfhi(g[j]) + fmaf(a0, w0.y, fmaf(a1, w1.y, bb.y)), 0.f); \
        }                                                                       \
        idx += 4;                                                               \
    }                                                                           \
    for (; idx < e1; ++idx) {                                                   \
        const unsigned long long m = MFETCH(idx);                               \
        const unsigned int g = hb[(size_t)(unsigned int)m * 64 + lane];         \
        const unsigned int ap = (unsigned int)(m >> 32);                        \
        const float a0 = bflo(ap), a1 = bfhi(ap);                               \
        acc.x += fmaxf(bflo(g) + fmaf(a0, w0.x, fmaf(a1, w1.x, bb.x)), 0.f);    \
        acc.y += fmaxf(bfhi(g) + fmaf(a0, w0.y, fmaf(a1, w1.y, bb.y)), 0.f);    \
    }

// ---------- Fused layer: LDS-staged meta + gather agg + 16x128 MFMA GEMM -----
// Block's meta range [off[nb], off[nb+16]) (~192 entries) is staged into LDS
// in ONE coalesced burst, removing the global-meta wait from the per-batch
// dependent chain (R14: meta-wait + gather-wait; now: lgkm + gather-wait).
__global__ __launch_bounds__(256) void layer_k(
    const unsigned int* __restrict__ hb,   // [N*64] bf16x2 node features (in)
    const unsigned long long* __restrict__ meta,
    const float* __restrict__ Wl,          // [2, HID]
    const float* __restrict__ bl,          // [HID]
    const int* __restrict__ off,
    const uint4* __restrict__ whf,         // this layer's [4][8][64] frags
    const uint4* __restrict__ wlf,
    const float* __restrict__ bias,        // [HID]
    float* __restrict__ out,               // f32 (final layer)
    unsigned short* __restrict__ hbo,      // bf16 (layers 0,1) — DISJOINT from hb
    const int last)
{
    __shared__ unsigned long long msh[MCAP];  // 4KB meta cache
    __shared__ unsigned int vsh[NPB * 68];    // 16 rows, pad 68
    const int tid = threadIdx.x;
    const int wave = tid >> 6;             // 0..3
    const int lane = tid & 63;
    const int nb = blockIdx.x * NPB;

    const int mbeg = off[nb];
    const int cnt = off[nb + NPB] - mbeg;
    for (int i = tid; i < cnt && i < MCAP; i += 256)
        msh[i] = meta[mbeg + i];

    const int f0 = lane << 1;
    const float2 w0 = *(const float2*)(Wl + f0);
    const float2 w1 = *(const float2*)(Wl + HID + f0);
    const float2 bb = *(const float2*)(bl + f0);
    __syncthreads();

    // ---- phase 1: aggregation, 4 nodes per wave, meta from LDS ----
    for (int i = 0; i < 4; ++i) {
        const int node = nb + wave * 4 + i;
        const unsigned int hp = hb[(size_t)node * 64 + lane];
        float2 acc = make_float2(bflo(hp), bfhi(hp));   // (1+eps)*h, eps=0
        int idx = off[node] - mbeg;
        const int e1 = off[node + 1] - mbeg;
        if (cnt <= MCAP) {
#define MF_LDS(I) msh[I]
            AGG_LOOP(MF_LDS)
#undef MF_LDS
        } else {                            // never taken for this input; correct
#define MF_GBL(I) meta[mbeg + (I)]
            AGG_LOOP(MF_GBL)
#undef MF_GBL
        }
        vsh[(wave * 4 + i) * 68 + lane] = f2bf(acc.x) | (f2bf(acc.y) << 16);
    }
    __syncthreads();

    // ---- phase 2: GEMM from LDS. all waves share the 16-row A tile; each
    // wave owns a 32-col quarter (2 MFMA col-tiles). ----
    const int lrow = lane & 15;            // local A row
    short8 a[4];
#pragma unroll
    for (int kt = 0; kt < 4; ++kt) {
        const uint4 t = *(const uint4*)&vsh[lrow * 68 + (kt * 4 + (lane >> 4)) * 4];
        a[kt] = *(const short8*)&t;
    }
    const int crow0 = nb + (lane >> 4) * 4;
    const int ncol = lane & 15;
#pragma unroll
    for (int ntl = 0; ntl < 2; ++ntl) {
        const int nt = wave * 2 + ntl;
        const float bv = bias[nt * 16 + ncol];
        f32x4 acc = {bv, bv, bv, bv};
#pragma unroll
        for (int kt = 0; kt < 4; ++kt) {
            uint4 th = whf[(kt * 8 + nt) * 64 + lane];
            uint4 tl = wlf[(kt * 8 + nt) * 64 + lane];
            acc = __builtin_amdgcn_mfma_f32_16x16x32_bf16(a[kt], *(short8*)&th, acc, 0, 0, 0);
            acc = __builtin_amdgcn_mfma_f32_16x16x32_bf16(a[kt], *(short8*)&tl, acc, 0, 0, 0);
        }
#pragma unroll
        for (int r = 0; r < 4; ++r) {
            const int rr = crow0 + r;
            float v = acc[r];
            v = v >= 0.f ? v : NEG * v;
            if (last) out[(size_t)rr * HID + nt * 16 + ncol] = v;
            else      hbo[(size_t)rr * HID + nt * 16 + ncol] = (unsigned short)f2bf(v);
        }
    }
}

extern "C" void kernel_launch(void* const* d_in, const int* in_sizes, int n_in,
                              void* d_out, int out_size, void* d_ws, size_t ws_size,
                              hipStream_t stream) {
    const float* x  = (const float*)d_in[0];
    const int*   ei = (const int*)d_in[1];
    const float* ea = (const float*)d_in[2];
    const float* Wl = (const float*)d_in[3];
    const float* bl = (const float*)d_in[4];
    const float* W  = (const float*)d_in[5];
    const float* b  = (const float*)d_in[6];

    float* h = (float*)d_out;                              // final f32 output

    unsigned long long* meta = (unsigned long long*)d_ws;  // [E] {src, a0|a1 bf16}
    unsigned int* hb0 = (unsigned int*)(meta + NEDGES);    // [N*64] features ping
    unsigned int* hb1 = hb0 + (size_t)NNODES * 64;         // [N*64] features pong
    uint4* whf = (uint4*)(hb1 + (size_t)NNODES * 64);      // [3][4][8][64]
    uint4* wlf = whf + NLAYERS * 4 * 8 * 64;
    int* off  = (int*)(wlf + NLAYERS * 4 * 8 * 64);        // [N+1] (doubles as histogram)
    int* cur  = off + NNODES + 1;
    int* part = cur + NNODES;
    int* bsum = part + NNODES;

    prep_k<<<CVT_B + ZERO_B + WCONV_B, 256, 0, stream>>>(x, hb0, off, W, whf, wlf);
    hist_k<<<(NEDGES + 255) / 256, 256, 0, stream>>>(ei, off);
    scan1_k<<<SCAN_B, 1024, 0, stream>>>(off, part, bsum);
    scan2_k<<<SCAN_B, 1024, 0, stream>>>(part, bsum, off, cur);
    fill_k<<<8 * FILL_BPG, 256, 0, stream>>>(ei, ea, cur, meta);

    unsigned int* hin = hb0;
    unsigned int* hout = hb1;
    for (int l = 0; l < NLAYERS; ++l) {
        layer_k<<<NNODES / NPB, 256, 0, stream>>>(
            hin, meta, Wl + (size_t)l * 2 * HID, bl + (size_t)l * HID, off,
            whf + (size_t)l * 4 * 8 * 64, wlf + (size_t)l * 4 * 8 * 64,
            b + (size_t)l * HID, h, (unsigned short*)hout, l == NLAYERS - 1);
        unsigned int* tmp = hin; hin = hout; hout = tmp;
    }
}